// Round 11
// baseline (503.864 us; speedup 1.0000x reference)
//
#include <hip/hip_runtime.h>
#include <hip/hip_bf16.h>

// GRUCell fused cell. B=16384, d=1024, 2d=2048.
//   inp  = LN(concat(x,h); g1,b1) * dm
//   gates= inp @ Wg + bg ; r=sig(gates[:, :d]); z=sig(gates[:, d:])
//   inp2 = LN(concat(x, h*r); g2,b2) * dm
//   u    = tanh(inp2 @ Wu + bu)
//   out  = h*z + (1-z)*u
//
// R11: corrected m201-faithful 8-phase GEMM (R6 retry with balanced phases
// and proven all-waves vmcnt discipline).
// Geometry: 256x256 tile, BK=64, 8 waves (2Mx4N, wave=128x64), 2x64KB dbuf.
// Regions per dbuf d: A.k0 @0, B.k0 @16K, A.k1 @32K, B.k1 @48K (16KB each;
// k-half = 32 of the 64-K tile; 256 rows x 32k x 2B).
// Iter i computes tile 2i (d0, Ph1-4) and 2i+1 (d1, Ph5-8).
// Phase p = {vmcnt(VM); [RDB4] RDA4; STG(1 half-tile, 2 gloads); barrier;
//            lgkm0; sched_barrier; setprio1; 16 MFMA; setprio0; barrier}
//   Ph1: d0.k0 mh0 (RDB)  stage d1.A.k1 <- t(2i+1)
//   Ph2: d0.k0 mh1        stage d1.B.k1 <- t(2i+1)
//   Ph3: d0.k1 mh0 (RDB)  stage d0.A.k0 <- t(2i+2)
//   Ph4: d0.k1 mh1        stage d0.B.k0 <- t(2i+2)
//   Ph5: d1.k0 mh0 (RDB)  stage d0.A.k1 <- t(2i+2)
//   Ph6: d1.k0 mh1        stage d0.B.k1 <- t(2i+2)
//   Ph7: d1.k1 mh0 (RDB)  stage d1.A.k0 <- t(2i+3)
//   Ph8: d1.k1 mh1        stage d1.B.k0 <- t(2i+3)
// Liveness (stage target dead >=1 phase before write): A regions last read
// at their mh1 phase, B regions last read at their RDB phase; every stage
// above targets a region whose last reader phase closed >=1 barrier earlier.
// Confirmation: region staged at phase s is read at s+5 or s+6. Own-wave:
// vmcnt(6) at p-top leaves the newest 3 stages (6 loads) outstanding ->
// confirms p-4 and older. All-waves: every wave passed vmcnt(6) at p-1-top
// (confirms p-5) AND barrier2(p-1) precedes p's reads -> regions >=5 phases
// old are globally visible. Min distance = 5. OK.
// Last iter (stages Ph3-8 skipped): VM = 6,6,6,4,4,0,0,0 (re-derived with
// the missing stages; Ph5 needs prev8 -> vmcnt(4) at Ph4; Ph7 needs Ph2 ->
// vmcnt(0) at Ph6).
// Prologue: stage d0 (4 halves, t0) + d1.k0 (2 halves, t1); vmcnt(6);
// barrier. (Confirms d0.k0/d0.A.k1 own-wave; all-waves via the barrier.)
// Swizzle (R2/R9 PMC-verified 0 conflicts): 64B rows, phys granule =
// logical ^ ((row>>1)&3); stage SOURCE pre-XORed, LDS dest linear
// (global_load_lds = wave base + lane*16), frag reads apply same XOR.
//
// ws layout (bytes):
//   [0,            8388608)  WgT  bf16 [2048][2048]  (WgT[n][k] = Wg[k][n])
//   [8388608,     12582912)  WuT  bf16 [1024][2048]
//   [12582912,    79691776)  ln   bf16 [16384][2048] (LN1 then LN2 output)
//   [79691776,   113246208)  hr   bf16 [16384][1024] (h * r)
// z (f32) staged in d_out between GEMM1 and GEMM2.

#define BATCH 16384
#define DDIM  1024
#define TWOD  2048
#define LNEPS 1e-5f

#define GBK 64
#define NTH 512

typedef __bf16 bf16x8 __attribute__((ext_vector_type(8)));
typedef float  f32x4  __attribute__((ext_vector_type(4)));
typedef unsigned short ushort4v __attribute__((ext_vector_type(4)));

__device__ __forceinline__ unsigned short f2bf(float f) {
    unsigned int u = __builtin_bit_cast(unsigned int, f);
    u = (u + 0x7FFFu + ((u >> 16) & 1u)) >> 16;   // round-to-nearest-even
    return (unsigned short)u;
}
__device__ __forceinline__ float bf2f(unsigned short s) {
    unsigned int u = ((unsigned int)s) << 16;
    return __builtin_bit_cast(float, u);
}
__device__ __forceinline__ void gload16(const void* g, void* l) {
    __builtin_amdgcn_global_load_lds((__attribute__((address_space(1))) void*)(g),
                                     (__attribute__((address_space(3))) void*)(l),
                                     16u, 0, 0);
}

// ---------------- weight transpose + f32->bf16 cast ------------------------
__global__ __launch_bounds__(256) void wtrans(const float* __restrict__ W,
                                              unsigned short* __restrict__ WT,
                                              int K, int N) {
    __shared__ float tile[32][33];
    const int k0 = blockIdx.x * 32;
    const int n0 = blockIdx.y * 32;
    const int tx = threadIdx.x & 31;
    const int ty = threadIdx.x >> 5;
#pragma unroll
    for (int p = 0; p < 32; p += 8)
        tile[p + ty][tx] = W[(size_t)(k0 + p + ty) * N + n0 + tx];
    __syncthreads();
#pragma unroll
    for (int p = 0; p < 32; p += 8)
        WT[(size_t)(n0 + p + ty) * K + k0 + tx] = f2bf(tile[tx][p + ty]);
}

// ---------------- fused LayerNorm over concat(x, second) -------------------
template <bool SECOND_BF16>
__global__ __launch_bounds__(256) void ln_kernel(const float* __restrict__ x,
                                                 const void* __restrict__ h2,
                                                 const float* __restrict__ g,
                                                 const float* __restrict__ bt,
                                                 const float* __restrict__ dm,
                                                 unsigned short* __restrict__ out) {
    const int row  = blockIdx.x;
    const int tid  = threadIdx.x;
    const int lane = tid & 63;
    const int w    = tid >> 6;

    const float4 xl = reinterpret_cast<const float4*>(x + (size_t)row * DDIM)[tid];
    float hv[4];
    if (SECOND_BF16) {
        const ushort4v hl = reinterpret_cast<const ushort4v*>(
            (const unsigned short*)h2 + (size_t)row * DDIM)[tid];
#pragma unroll
        for (int j = 0; j < 4; ++j) hv[j] = bf2f(hl[j]);
    } else {
        const float4 hl = reinterpret_cast<const float4*>(
            (const float*)h2 + (size_t)row * DDIM)[tid];
        hv[0] = hl.x; hv[1] = hl.y; hv[2] = hl.z; hv[3] = hl.w;
    }
    float xv[4] = {xl.x, xl.y, xl.z, xl.w};

    float s = 0.f, ss = 0.f;
#pragma unroll
    for (int j = 0; j < 4; ++j) { s += xv[j] + hv[j]; ss += xv[j]*xv[j] + hv[j]*hv[j]; }
#pragma unroll
    for (int o = 32; o; o >>= 1) { s += __shfl_xor(s, o); ss += __shfl_xor(ss, o); }
    __shared__ float red[8];
    if (lane == 0) { red[w] = s; red[4 + w] = ss; }
    __syncthreads();
    s  = red[0] + red[1] + red[2] + red[3];
    ss = red[4] + red[5] + red[6] + red[7];
    const float inv  = 1.0f / (float)TWOD;
    const float mu   = s * inv;
    const float var  = ss * inv - mu * mu;
    const float rstd = rsqrtf(var + LNEPS);

    {
        const float4 gv = reinterpret_cast<const float4*>(g)[tid];
        const float4 bv = reinterpret_cast<const float4*>(bt)[tid];
        const float4 dv = reinterpret_cast<const float4*>(dm)[tid];
        ushort4v pk;
        pk[0] = f2bf(((xv[0] - mu) * rstd * gv.x + bv.x) * dv.x);
        pk[1] = f2bf(((xv[1] - mu) * rstd * gv.y + bv.y) * dv.y);
        pk[2] = f2bf(((xv[2] - mu) * rstd * gv.z + bv.z) * dv.z);
        pk[3] = f2bf(((xv[3] - mu) * rstd * gv.w + bv.w) * dv.w);
        reinterpret_cast<ushort4v*>(out + (size_t)row * TWOD)[tid] = pk;
    }
    {
        const float4 gv = reinterpret_cast<const float4*>(g)[256 + tid];
        const float4 bv = reinterpret_cast<const float4*>(bt)[256 + tid];
        const float4 dv = reinterpret_cast<const float4*>(dm)[256 + tid];
        ushort4v pk;
        pk[0] = f2bf(((hv[0] - mu) * rstd * gv.x + bv.x) * dv.x);
        pk[1] = f2bf(((hv[1] - mu) * rstd * gv.y + bv.y) * dv.y);
        pk[2] = f2bf(((hv[2] - mu) * rstd * gv.z + bv.z) * dv.z);
        pk[3] = f2bf(((hv[3] - mu) * rstd * gv.w + bv.w) * dv.w);
        reinterpret_cast<ushort4v*>(out + (size_t)row * TWOD + DDIM)[tid] = pk;
    }
}

// ---------------- 256x256 8-wave 8-phase bf16 GEMM (m201 port) -------------
template <int EPI>
__global__ __launch_bounds__(NTH, 2) void gemm8p(const unsigned short* __restrict__ A,
                                                 const unsigned short* __restrict__ BT,
                                                 const float* __restrict__ bias,
                                                 const float* __restrict__ h,
                                                 unsigned short* __restrict__ hr,
                                                 float* __restrict__ zbuf,
                                                 float* __restrict__ outp,
                                                 int NYB) {
    extern __shared__ char sm[];      // 131072
    const int tid  = threadIdx.x;
    const int lane = tid & 63;
    const int w    = tid >> 6;        // 0..7
    const int wm   = w >> 2;          // 0..1 (M: 128 rows)
    const int wn   = w & 3;           // 0..3 (N: 64 cols)
    const int q    = lane >> 4;       // 0..3
    const int r16  = lane & 15;

    // XCD-chunk swizzle (bijective: nwg % 8 == 0), y(N)-fastest decode
    const int nwg = gridDim.x;
    const int cid = (blockIdx.x & 7) * (nwg >> 3) + (blockIdx.x >> 3);
    const size_t m0 = (size_t)(cid / NYB) * 256;
    const int    n0 = (cid % NYB) * 256;

    const unsigned short* Ag = A  + m0 * TWOD;
    const unsigned short* Bg = BT + (size_t)n0 * TWOD;

    // staging: half-tile = 256 rows x 4 granules(16B) = 1024 granules;
    // thread t covers granules t (rows 0..127) and t+512 (rows 128..255).
    const int rg0 = tid >> 2;                        // 0..127
    const int sg  = (tid & 3) ^ ((rg0 >> 1) & 3);    // parity same for +128
    const unsigned short* aS0 = Ag + (size_t)rg0 * TWOD + sg * 8;
    const unsigned short* aS1 = Ag + (size_t)(rg0 + 128) * TWOD + sg * 8;
    const unsigned short* bS0 = Bg + (size_t)rg0 * TWOD + sg * 8;
    const unsigned short* bS1 = Bg + (size_t)(rg0 + 128) * TWOD + sg * 8;
    const unsigned woff = (unsigned)w * 1024u;       // + lane*16 by HW

#define RG(d, kh, isB) ((unsigned)(d)*65536u + (unsigned)(kh)*32768u + (unsigned)(isB)*16384u)
#define STG(isB, T, kh, d) { \
    const unsigned b_ = RG(d, kh, isB) + woff; \
    const int ko_ = (T) * GBK + (kh) * 32; \
    gload16(((isB) ? bS0 : aS0) + ko_, sm + b_); \
    gload16(((isB) ? bS1 : aS1) + ko_, sm + b_ + 8192u); }

    // frag reads (phys granule = q ^ ((r16>>1)&3); rows = mult16 + r16)
    const unsigned pgo  = (unsigned)((q ^ ((r16 >> 1) & 3)) * 16);
    const unsigned abase = (unsigned)((wm * 128 + r16) * 64) + pgo;  // + (mh*64+mi*16)*64
    const unsigned bbase = (unsigned)((wn * 64 + r16) * 64) + pgo;   // + n*16*64

#define VMC(N) asm volatile("s_waitcnt vmcnt(" #N ")" ::: "memory")
#define BARR   __builtin_amdgcn_s_barrier()
#define LGKM0  asm volatile("s_waitcnt lgkmcnt(0)" ::: "memory")
#define RDA4(d, kh, mh) { _Pragma("unroll") for (int mi = 0; mi < 4; ++mi) \
    af[mi] = *(const bf16x8*)(sm + RG(d, kh, 0) + abase + (unsigned)((mh)*64 + mi*16) * 64u); }
#define RDB4(d, kh) { _Pragma("unroll") for (int n = 0; n < 4; ++n) \
    bf[n] = *(const bf16x8*)(sm + RG(d, kh, 1) + bbase + (unsigned)(n*16) * 64u); }
#define MFMA16(mh) { __builtin_amdgcn_sched_barrier(0); \
    __builtin_amdgcn_s_setprio(1); \
    _Pragma("unroll") for (int mi = 0; mi < 4; ++mi) \
      _Pragma("unroll") for (int n = 0; n < 4; ++n) \
        acc[(mh)*4+mi][n] = __builtin_amdgcn_mfma_f32_16x16x32_bf16(af[mi], bf[n], acc[(mh)*4+mi][n], 0, 0, 0); \
    __builtin_amdgcn_s_setprio(0); }

    bf16x8 af[4], bf[4];
    f32x4 acc[8][4] = {};
    const int NT = TWOD / GBK;   // 32
    const int NI = NT / 2;       // 16

    // prologue: d0 <- t0 (4 halves), d1.k0 <- t1 (2 halves)
    STG(0, 0, 0, 0); STG(1, 0, 0, 0); STG(0, 0, 1, 0); STG(1, 0, 1, 0);
    STG(0, 1, 0, 1); STG(1, 1, 0, 1);
    VMC(6); BARR;

#pragma unroll 1
    for (int it = 0; it < NI; ++it) {
        const int t1 = 2 * it + 1, t2 = 2 * it + 2, t3 = 2 * it + 3;
        const bool lastI = (it == NI - 1);
        // Ph1: d0.k0 mh0
        VMC(6); RDB4(0, 0); RDA4(0, 0, 0); STG(0, t1, 1, 1);
        BARR; LGKM0; MFMA16(0); BARR;
        // Ph2: d0.k0 mh1
        VMC(6); RDA4(0, 0, 1); STG(1, t1, 1, 1);
        BARR; LGKM0; MFMA16(1); BARR;
        // Ph3: d0.k1 mh0
        VMC(6); RDB4(0, 1); RDA4(0, 1, 0); if (!lastI) STG(0, t2, 0, 0);
        BARR; LGKM0; MFMA16(0); BARR;
        // Ph4: d0.k1 mh1
        if (lastI) { VMC(4); } else { VMC(6); }
        RDA4(0, 1, 1); if (!lastI) STG(1, t2, 0, 0);
        BARR; LGKM0; MFMA16(1); BARR;
        // Ph5: d1.k0 mh0
        if (lastI) { VMC(4); } else { VMC(6); }
        RDB4(1, 0); RDA4(1, 0, 0); if (!lastI) STG(0, t2, 1, 0);
        BARR; LGKM0; MFMA16(0); BARR;
        // Ph6: d1.k0 mh1
        if (lastI) { VMC(0); } else { VMC(6); }
        RDA4(1, 0, 1); if (!lastI) STG(1, t2, 1, 0);
        BARR; LGKM0; MFMA16(1); BARR;
        // Ph7: d1.k1 mh0
        if (lastI) { VMC(0); } else { VMC(6); }
        RDB4(1, 1); RDA4(1, 1, 0); if (!lastI) STG(0, t3, 0, 1);
        BARR; LGKM0; MFMA16(0); BARR;
        // Ph8: d1.k1 mh1
        if (lastI) { VMC(0); } else { VMC(6); }
        RDA4(1, 1, 1); if (!lastI) STG(1, t3, 0, 1);
        BARR; LGKM0; MFMA16(1); BARR;
    }

    // epilogue: D col = lane&15, row = (lane>>4)*4 + reg  [verified m89/m91]
#pragma unroll
    for (int n = 0; n < 4; ++n) {
        const int col = n0 + wn * 64 + n * 16 + r16;
        const float bc = bias[col];
#pragma unroll
        for (int m = 0; m < 8; ++m) {
#pragma unroll
            for (int rg = 0; rg < 4; ++rg) {
                const size_t row = m0 + wm * 128 + (m >> 2) * 64 + (m & 3) * 16 + q * 4 + rg;
                const float v = acc[m][n][rg] + bc;
                if (EPI == 0) {
                    if (col < DDIM) {
                        const float rr = 1.0f / (1.0f + __expf(-v));
                        const size_t idx = row * DDIM + col;
                        hr[idx] = f2bf(h[idx] * rr);
                    } else {
                        const float zz = 1.0f / (1.0f + __expf(-v));
                        zbuf[row * DDIM + (col - DDIM)] = zz;
                    }
                } else {
                    const float u = tanhf(v);
                    const size_t idx = row * DDIM + col;
                    const float zz = zbuf[idx];
                    const float hv = h[idx];
                    outp[idx] = hv * zz + (1.0f - zz) * u;
                }
            }
        }
    }
#undef RG
#undef STG
#undef VMC
#undef BARR
#undef LGKM0
#undef RDA4
#undef RDB4
#undef MFMA16
}

// --------------------------------------------------------------------------
extern "C" void kernel_launch(void* const* d_in, const int* in_sizes, int n_in,
                              void* d_out, int out_size, void* d_ws, size_t ws_size,
                              hipStream_t stream) {
    const float* x  = (const float*)d_in[0];
    const float* h  = (const float*)d_in[1];
    const float* Wg = (const float*)d_in[2];
    const float* bg = (const float*)d_in[3];
    const float* Wu = (const float*)d_in[4];
    const float* bu = (const float*)d_in[5];
    const float* g1 = (const float*)d_in[6];
    const float* b1 = (const float*)d_in[7];
    const float* g2 = (const float*)d_in[8];
    const float* b2 = (const float*)d_in[9];
    const float* dm = (const float*)d_in[10];
    float* out = (float*)d_out;

    char* ws = (char*)d_ws;
    unsigned short* WgT = (unsigned short*)(ws);                    // 8 MB
    unsigned short* WuT = (unsigned short*)(ws + 8388608);          // 4 MB
    unsigned short* ln  = (unsigned short*)(ws + 12582912);         // 64 MB
    unsigned short* hr  = (unsigned short*)(ws + 79691776);         // 32 MB

    hipFuncSetAttribute((const void*)gemm8p<0>,
                        hipFuncAttributeMaxDynamicSharedMemorySize, 131072);
    hipFuncSetAttribute((const void*)gemm8p<1>,
                        hipFuncAttributeMaxDynamicSharedMemorySize, 131072);

    wtrans<<<dim3(64, 64), 256, 0, stream>>>(Wg, WgT, TWOD, TWOD);
    wtrans<<<dim3(64, 32), 256, 0, stream>>>(Wu, WuT, TWOD, DDIM);
    ln_kernel<false><<<BATCH, 256, 0, stream>>>(x, (const void*)h, g1, b1, dm, ln);
    // GEMM1: 64 M-blocks x 8 N-blocks = 512 (div 8 ok)
    gemm8p<0><<<512, NTH, 131072, stream>>>(ln, WgT, bg, h, hr, out, nullptr, 8);
    ln_kernel<true><<<BATCH, 256, 0, stream>>>(x, (const void*)hr, g2, b2, dm, ln);
    // GEMM2: 64 x 4 = 256 (div 8 ok)
    gemm8p<1><<<256, NTH, 131072, stream>>>(ln, WuT, bu, h, nullptr, out, out, 4);
}

// Round 12
// 428.860 us; speedup vs baseline: 1.1749x; 1.1749x over previous
//
#include <hip/hip_runtime.h>
#include <hip/hip_bf16.h>

// GRUCell fused cell. B=16384, d=1024, 2d=2048.
//   inp  = LN(concat(x,h); g1,b1) * dm
//   gates= inp @ Wg + bg ; r=sig(gates[:, :d]); z=sig(gates[:, d:])
//   inp2 = LN(concat(x, h*r); g2,b2) * dm
//   u    = tanh(inp2 @ Wu + bu)
//   out  = h*z + (1-z)*u
//
// R12: best-known GEMM base (R9-class m97 structure, 64x64 wave tile,
// XCD chunk swizzle, granule-XOR swizzle pair) + two levers:
//  (1) stage-ahead double-buffer at PRESERVED occupancy: BK=32, 2x16KB LDS
//      (32KB -> up to 5 blocks/CU). {STAGE(T+1 -> buf^1); read+MFMA(buf);
//      __syncthreads}. The drain at each barrier is covered by the MFMA
//      phase + 4-5 co-resident blocks (R10's regression was confounded by
//      its 2-blk/CU occupancy loss; this isolates the pipeline).
//      Safety: stage(T+1) targets buf^1 (not read this iter); iter T+1's
//      stage targets the buffer all waves finished reading at barrier T;
//      __syncthreads drains each wave's own gloads (vmcnt0) before release
//      -> all-waves visibility.
//  (2) guarded traffic trims (only if ws_size >= 180355072, else exact
//      R9 semantics): LN1 emits h in bf16 (hb, 32MB) used by both GEMM
//      epilogues (-64MB reads); z staged bf16 in ws (-96MB round trip vs
//      f32-in-d_out). Worst-case absmax adds ~0.03 on 0.0156 (thr 0.084).
//
// ws layout (bytes):
//   [0,            8388608)  WgT bf16 [2048][2048]
//   [8388608,     12582912)  WuT bf16 [1024][2048]
//   [12582912,    79691776)  ln  bf16 [16384][2048]
//   [79691776,   113246208)  hr  bf16 [16384][1024]
//   [113246208,  146800640)  zb  bf16 [16384][1024]   (big-ws only)
//   [146800640,  180355072)  hb  bf16 [16384][1024]   (big-ws only)

#define BATCH 16384
#define DDIM  1024
#define TWOD  2048
#define LNEPS 1e-5f

#define GBK 32
#define NTH 256
#define BUFB 16384u

typedef __bf16 bf16x8 __attribute__((ext_vector_type(8)));
typedef float  f32x4  __attribute__((ext_vector_type(4)));
typedef unsigned short ushort4v __attribute__((ext_vector_type(4)));

__device__ __forceinline__ unsigned short f2bf(float f) {
    unsigned int u = __builtin_bit_cast(unsigned int, f);
    u = (u + 0x7FFFu + ((u >> 16) & 1u)) >> 16;   // round-to-nearest-even
    return (unsigned short)u;
}
__device__ __forceinline__ float bf2f(unsigned short s) {
    unsigned int u = ((unsigned int)s) << 16;
    return __builtin_bit_cast(float, u);
}
__device__ __forceinline__ void gload16(const void* g, void* l) {
    __builtin_amdgcn_global_load_lds((__attribute__((address_space(1))) void*)(g),
                                     (__attribute__((address_space(3))) void*)(l),
                                     16u, 0, 0);
}

// ---------------- weight transpose + f32->bf16 cast ------------------------
__global__ __launch_bounds__(256) void wtrans(const float* __restrict__ W,
                                              unsigned short* __restrict__ WT,
                                              int K, int N) {
    __shared__ float tile[32][33];
    const int k0 = blockIdx.x * 32;
    const int n0 = blockIdx.y * 32;
    const int tx = threadIdx.x & 31;
    const int ty = threadIdx.x >> 5;
#pragma unroll
    for (int p = 0; p < 32; p += 8)
        tile[p + ty][tx] = W[(size_t)(k0 + p + ty) * N + n0 + tx];
    __syncthreads();
#pragma unroll
    for (int p = 0; p < 32; p += 8)
        WT[(size_t)(n0 + p + ty) * K + k0 + tx] = f2bf(tile[tx][p + ty]);
}

// ---------------- fused LayerNorm over concat(x, second) -------------------
// hb_out != null (LN1 big-ws mode): also emit the h-half as bf16.
template <bool SECOND_BF16>
__global__ __launch_bounds__(256) void ln_kernel(const float* __restrict__ x,
                                                 const void* __restrict__ h2,
                                                 const float* __restrict__ g,
                                                 const float* __restrict__ bt,
                                                 const float* __restrict__ dm,
                                                 unsigned short* __restrict__ out,
                                                 unsigned short* __restrict__ hb_out) {
    const int row  = blockIdx.x;
    const int tid  = threadIdx.x;
    const int lane = tid & 63;
    const int w    = tid >> 6;

    const float4 xl = reinterpret_cast<const float4*>(x + (size_t)row * DDIM)[tid];
    float hv[4];
    if (SECOND_BF16) {
        const ushort4v hl = reinterpret_cast<const ushort4v*>(
            (const unsigned short*)h2 + (size_t)row * DDIM)[tid];
#pragma unroll
        for (int j = 0; j < 4; ++j) hv[j] = bf2f(hl[j]);
    } else {
        const float4 hl = reinterpret_cast<const float4*>(
            (const float*)h2 + (size_t)row * DDIM)[tid];
        hv[0] = hl.x; hv[1] = hl.y; hv[2] = hl.z; hv[3] = hl.w;
    }
    float xv[4] = {xl.x, xl.y, xl.z, xl.w};

    if (!SECOND_BF16 && hb_out) {
        ushort4v hp;
#pragma unroll
        for (int j = 0; j < 4; ++j) hp[j] = f2bf(hv[j]);
        reinterpret_cast<ushort4v*>(hb_out + (size_t)row * DDIM)[tid] = hp;
    }

    float s = 0.f, ss = 0.f;
#pragma unroll
    for (int j = 0; j < 4; ++j) { s += xv[j] + hv[j]; ss += xv[j]*xv[j] + hv[j]*hv[j]; }
#pragma unroll
    for (int o = 32; o; o >>= 1) { s += __shfl_xor(s, o); ss += __shfl_xor(ss, o); }
    __shared__ float red[8];
    if (lane == 0) { red[w] = s; red[4 + w] = ss; }
    __syncthreads();
    s  = red[0] + red[1] + red[2] + red[3];
    ss = red[4] + red[5] + red[6] + red[7];
    const float inv  = 1.0f / (float)TWOD;
    const float mu   = s * inv;
    const float var  = ss * inv - mu * mu;
    const float rstd = rsqrtf(var + LNEPS);

    {
        const float4 gv = reinterpret_cast<const float4*>(g)[tid];
        const float4 bv = reinterpret_cast<const float4*>(bt)[tid];
        const float4 dv = reinterpret_cast<const float4*>(dm)[tid];
        ushort4v pk;
        pk[0] = f2bf(((xv[0] - mu) * rstd * gv.x + bv.x) * dv.x);
        pk[1] = f2bf(((xv[1] - mu) * rstd * gv.y + bv.y) * dv.y);
        pk[2] = f2bf(((xv[2] - mu) * rstd * gv.z + bv.z) * dv.z);
        pk[3] = f2bf(((xv[3] - mu) * rstd * gv.w + bv.w) * dv.w);
        reinterpret_cast<ushort4v*>(out + (size_t)row * TWOD)[tid] = pk;
    }
    {
        const float4 gv = reinterpret_cast<const float4*>(g)[256 + tid];
        const float4 bv = reinterpret_cast<const float4*>(bt)[256 + tid];
        const float4 dv = reinterpret_cast<const float4*>(dm)[256 + tid];
        ushort4v pk;
        pk[0] = f2bf(((hv[0] - mu) * rstd * gv.x + bv.x) * dv.x);
        pk[1] = f2bf(((hv[1] - mu) * rstd * gv.y + bv.y) * dv.y);
        pk[2] = f2bf(((hv[2] - mu) * rstd * gv.z + bv.z) * dv.z);
        pk[3] = f2bf(((hv[3] - mu) * rstd * gv.w + bv.w) * dv.w);
        reinterpret_cast<ushort4v*>(out + (size_t)row * TWOD + DDIM)[tid] = pk;
    }
}

// ---------------- 128x128 dbuf stage-ahead bf16 GEMM -----------------------
// A : [16384][2048] bf16 row-major; BT: [N][2048] bf16 row-major.
// LDS: 2 x 16KB buffers {A[128][32] @0, B[128][32] @8K}. Granule-XOR
// swizzle pair (phys granule = logical ^ ((row>>1)&3)), PMC-verified 0
// conflicts. Grid 1D, XCD-chunk swizzled, y(N)-fastest decode.
template <int EPI>
__global__ __launch_bounds__(NTH, 4) void gemmdb(const unsigned short* __restrict__ A,
                                                 const unsigned short* __restrict__ BT,
                                                 const float* __restrict__ bias,
                                                 const float* __restrict__ h,
                                                 const unsigned short* __restrict__ hb,
                                                 unsigned short* __restrict__ hr,
                                                 unsigned short* __restrict__ zb,
                                                 float* __restrict__ zf,
                                                 float* __restrict__ outp,
                                                 int NYB) {
    __shared__ char sm[32768];
    const int tid  = threadIdx.x;
    const int lane = tid & 63;
    const int w    = tid >> 6;        // 0..3
    const int wm   = w >> 1;          // 0..1
    const int wn   = w & 1;           // 0..1
    const int q    = lane >> 4;       // 0..3
    const int r16  = lane & 15;

    const int nwg = gridDim.x;
    const int cid = (blockIdx.x & 7) * (nwg >> 3) + (blockIdx.x >> 3);
    const size_t m0 = (size_t)(cid / NYB) * 128;
    const int    n0 = (cid % NYB) * 128;

    const unsigned short* Ag = A  + m0 * TWOD;
    const unsigned short* Bg = BT + (size_t)n0 * TWOD;

    // staging: 512 granules/operand; thread t covers granules t, t+256
    // (rows rg0, rg0+64; same swizzle parity). Source pre-XORed, dest linear.
    const int rg0 = tid >> 2;
    const int sg  = (tid & 3) ^ ((rg0 >> 1) & 3);
    const unsigned short* a0 = Ag + (size_t)rg0 * TWOD + sg * 8;
    const unsigned short* a1 = Ag + (size_t)(rg0 + 64) * TWOD + sg * 8;
    const unsigned short* b0 = Bg + (size_t)rg0 * TWOD + sg * 8;
    const unsigned short* b1 = Bg + (size_t)(rg0 + 64) * TWOD + sg * 8;
    const unsigned dst = (unsigned)w * 1024u;        // + lane*16 by HW

#define STAGE(base, T) { const int k_ = (T) * GBK; \
    gload16(a0 + k_, sm + (base) + dst); \
    gload16(a1 + k_, sm + (base) + dst + 4096u); \
    gload16(b0 + k_, sm + (base) + 8192u + dst); \
    gload16(b1 + k_, sm + (base) + 8192u + dst + 4096u); }

    const unsigned pgo  = (unsigned)((q ^ ((r16 >> 1) & 3)) * 16);
    const unsigned arow = (unsigned)((wm * 64 + r16) * 64) + pgo;            // + i*1024
    const unsigned brow = 8192u + (unsigned)((wn * 64 + r16) * 64) + pgo;    // + n*1024

    f32x4 acc[4][4] = {};
    const int NT = TWOD / GBK;   // 64

    STAGE(0u, 0);
    __syncthreads();

    unsigned cur = 0u;
#pragma unroll 1
    for (int T = 0; T < NT; ++T) {
        if (T + 1 < NT) STAGE(cur ^ BUFB, T + 1);   // flies under MFMA below
        bf16x8 af[4], bfr[4];
#pragma unroll
        for (int n = 0; n < 4; ++n)
            bfr[n] = *(const bf16x8*)(sm + cur + brow + (unsigned)n * 1024u);
#pragma unroll
        for (int i = 0; i < 4; ++i)
            af[i] = *(const bf16x8*)(sm + cur + arow + (unsigned)i * 1024u);
#pragma unroll
        for (int i = 0; i < 4; ++i)
#pragma unroll
            for (int n = 0; n < 4; ++n)
                acc[i][n] = __builtin_amdgcn_mfma_f32_16x16x32_bf16(af[i], bfr[n], acc[i][n], 0, 0, 0);
        __syncthreads();   // drains stage(T+1); covered by MFMA + co-resident blocks
        cur ^= BUFB;
    }

    // epilogue: D col = lane&15, row = (lane>>4)*4 + reg  [verified m89/m91]
#pragma unroll
    for (int n = 0; n < 4; ++n) {
        const int col = n0 + wn * 64 + n * 16 + r16;
        const float bc = bias[col];
#pragma unroll
        for (int m = 0; m < 4; ++m) {
#pragma unroll
            for (int rg = 0; rg < 4; ++rg) {
                const size_t row = m0 + wm * 64 + m * 16 + q * 4 + rg;
                const float v = acc[m][n][rg] + bc;
                if (EPI == 0) {
                    if (col < DDIM) {
                        const float rr = 1.0f / (1.0f + __expf(-v));
                        const size_t idx = row * DDIM + col;
                        const float hvv = hb ? bf2f(hb[idx]) : h[idx];
                        hr[idx] = f2bf(hvv * rr);
                    } else {
                        const float zz = 1.0f / (1.0f + __expf(-v));
                        const size_t zi = row * DDIM + (col - DDIM);
                        if (zb) zb[zi] = f2bf(zz); else zf[zi] = zz;
                    }
                } else {
                    const float u = tanhf(v);
                    const size_t idx = row * DDIM + col;
                    const float zz = zb ? bf2f(zb[idx]) : zf[idx];
                    const float hv = hb ? bf2f(hb[idx]) : h[idx];
                    outp[idx] = hv * zz + (1.0f - zz) * u;
                }
            }
        }
    }
#undef STAGE
}

// --------------------------------------------------------------------------
extern "C" void kernel_launch(void* const* d_in, const int* in_sizes, int n_in,
                              void* d_out, int out_size, void* d_ws, size_t ws_size,
                              hipStream_t stream) {
    const float* x  = (const float*)d_in[0];
    const float* h  = (const float*)d_in[1];
    const float* Wg = (const float*)d_in[2];
    const float* bg = (const float*)d_in[3];
    const float* Wu = (const float*)d_in[4];
    const float* bu = (const float*)d_in[5];
    const float* g1 = (const float*)d_in[6];
    const float* b1 = (const float*)d_in[7];
    const float* g2 = (const float*)d_in[8];
    const float* b2 = (const float*)d_in[9];
    const float* dm = (const float*)d_in[10];
    float* out = (float*)d_out;

    char* ws = (char*)d_ws;
    unsigned short* WgT = (unsigned short*)(ws);                    // 8 MB
    unsigned short* WuT = (unsigned short*)(ws + 8388608);          // 4 MB
    unsigned short* ln  = (unsigned short*)(ws + 12582912);         // 64 MB
    unsigned short* hr  = (unsigned short*)(ws + 79691776);         // 32 MB
    const bool big = (ws_size >= 180355072ull);
    unsigned short* zb = big ? (unsigned short*)(ws + 113246208) : nullptr;
    unsigned short* hb = big ? (unsigned short*)(ws + 146800640) : nullptr;

    wtrans<<<dim3(64, 64), 256, 0, stream>>>(Wg, WgT, TWOD, TWOD);
    wtrans<<<dim3(64, 32), 256, 0, stream>>>(Wu, WuT, TWOD, DDIM);
    ln_kernel<false><<<BATCH, 256, 0, stream>>>(x, (const void*)h, g1, b1, dm, ln, hb);
    // GEMM1: 128 M x 16 N = 2048 blocks (div 8 ok)
    gemmdb<0><<<2048, NTH, 0, stream>>>(ln, WgT, bg, h, hb, hr, zb, out, nullptr, 16);
    ln_kernel<true><<<BATCH, 256, 0, stream>>>(x, (const void*)hr, g2, b2, dm, ln, nullptr);
    // GEMM2: 128 M x 8 N = 1024 blocks (div 8 ok)
    gemmdb<1><<<1024, NTH, 0, stream>>>(ln, WuT, bu, h, hb, nullptr, zb, out, out, 8);
}

// Round 13
// 382.538 us; speedup vs baseline: 1.3172x; 1.1211x over previous
//
#include <hip/hip_runtime.h>
#include <hip/hip_bf16.h>

// GRUCell fused cell. B=16384, d=1024, 2d=2048.
//   inp  = LN(concat(x,h); g1,b1) * dm
//   gates= inp @ Wg + bg ; r=sig(gates[:, :d]); z=sig(gates[:, d:])
//   inp2 = LN(concat(x, h*r); g2,b2) * dm
//   u    = tanh(inp2 @ Wu + bu)
//   out  = h*z + (1-z)*u
//
// R13 = R9 GEMM (best measured: BK=64 m97-structure, single buffer,
// immediate-drain __syncthreads, 3 blk/CU, granule-XOR swizzle pair,
// XCD chunk swizzle) + R12's guarded bf16 traffic trims (hb emitted once
// by LN1; z staged bf16 in ws instead of f32 via d_out). R12 proved the
// trims correct (absmax 0.0313 < 0.084) but its BK=32 dbuf GEMM regressed
// (246/243 us vs R9's 216/~110) -> revert the GEMM, keep the trims.
//
// ws layout (bytes):
//   [0,            8388608)  WgT bf16 [2048][2048]
//   [8388608,     12582912)  WuT bf16 [1024][2048]
//   [12582912,    79691776)  ln  bf16 [16384][2048]
//   [79691776,   113246208)  hr  bf16 [16384][1024]
//   [113246208,  146800640)  zb  bf16 [16384][1024]   (big-ws only)
//   [146800640,  180355072)  hb  bf16 [16384][1024]   (big-ws only)

#define BATCH 16384
#define DDIM  1024
#define TWOD  2048
#define LNEPS 1e-5f

#define GBK 64
#define NTH 256

typedef __bf16 bf16x8 __attribute__((ext_vector_type(8)));
typedef float  f32x4  __attribute__((ext_vector_type(4)));
typedef unsigned short ushort4v __attribute__((ext_vector_type(4)));

__device__ __forceinline__ unsigned short f2bf(float f) {
    unsigned int u = __builtin_bit_cast(unsigned int, f);
    u = (u + 0x7FFFu + ((u >> 16) & 1u)) >> 16;   // round-to-nearest-even
    return (unsigned short)u;
}
__device__ __forceinline__ float bf2f(unsigned short s) {
    unsigned int u = ((unsigned int)s) << 16;
    return __builtin_bit_cast(float, u);
}
__device__ __forceinline__ void gload16(const void* g, void* l) {
    __builtin_amdgcn_global_load_lds((__attribute__((address_space(1))) void*)(g),
                                     (__attribute__((address_space(3))) void*)(l),
                                     16u, 0, 0);
}

// ---------------- weight transpose + f32->bf16 cast ------------------------
__global__ __launch_bounds__(256) void wtrans(const float* __restrict__ W,
                                              unsigned short* __restrict__ WT,
                                              int K, int N) {
    __shared__ float tile[32][33];
    const int k0 = blockIdx.x * 32;
    const int n0 = blockIdx.y * 32;
    const int tx = threadIdx.x & 31;
    const int ty = threadIdx.x >> 5;
#pragma unroll
    for (int p = 0; p < 32; p += 8)
        tile[p + ty][tx] = W[(size_t)(k0 + p + ty) * N + n0 + tx];
    __syncthreads();
#pragma unroll
    for (int p = 0; p < 32; p += 8)
        WT[(size_t)(n0 + p + ty) * K + k0 + tx] = f2bf(tile[tx][p + ty]);
}

// ---------------- fused LayerNorm over concat(x, second) -------------------
// hb_out != null (LN1 big-ws mode): also emit the h-half as bf16.
template <bool SECOND_BF16>
__global__ __launch_bounds__(256) void ln_kernel(const float* __restrict__ x,
                                                 const void* __restrict__ h2,
                                                 const float* __restrict__ g,
                                                 const float* __restrict__ bt,
                                                 const float* __restrict__ dm,
                                                 unsigned short* __restrict__ out,
                                                 unsigned short* __restrict__ hb_out) {
    const int row  = blockIdx.x;
    const int tid  = threadIdx.x;
    const int lane = tid & 63;
    const int w    = tid >> 6;

    const float4 xl = reinterpret_cast<const float4*>(x + (size_t)row * DDIM)[tid];
    float hv[4];
    if (SECOND_BF16) {
        const ushort4v hl = reinterpret_cast<const ushort4v*>(
            (const unsigned short*)h2 + (size_t)row * DDIM)[tid];
#pragma unroll
        for (int j = 0; j < 4; ++j) hv[j] = bf2f(hl[j]);
    } else {
        const float4 hl = reinterpret_cast<const float4*>(
            (const float*)h2 + (size_t)row * DDIM)[tid];
        hv[0] = hl.x; hv[1] = hl.y; hv[2] = hl.z; hv[3] = hl.w;
    }
    float xv[4] = {xl.x, xl.y, xl.z, xl.w};

    if (!SECOND_BF16 && hb_out) {
        ushort4v hp;
#pragma unroll
        for (int j = 0; j < 4; ++j) hp[j] = f2bf(hv[j]);
        reinterpret_cast<ushort4v*>(hb_out + (size_t)row * DDIM)[tid] = hp;
    }

    float s = 0.f, ss = 0.f;
#pragma unroll
    for (int j = 0; j < 4; ++j) { s += xv[j] + hv[j]; ss += xv[j]*xv[j] + hv[j]*hv[j]; }
#pragma unroll
    for (int o = 32; o; o >>= 1) { s += __shfl_xor(s, o); ss += __shfl_xor(ss, o); }
    __shared__ float red[8];
    if (lane == 0) { red[w] = s; red[4 + w] = ss; }
    __syncthreads();
    s  = red[0] + red[1] + red[2] + red[3];
    ss = red[4] + red[5] + red[6] + red[7];
    const float inv  = 1.0f / (float)TWOD;
    const float mu   = s * inv;
    const float var  = ss * inv - mu * mu;
    const float rstd = rsqrtf(var + LNEPS);

    {
        const float4 gv = reinterpret_cast<const float4*>(g)[tid];
        const float4 bv = reinterpret_cast<const float4*>(bt)[tid];
        const float4 dv = reinterpret_cast<const float4*>(dm)[tid];
        ushort4v pk;
        pk[0] = f2bf(((xv[0] - mu) * rstd * gv.x + bv.x) * dv.x);
        pk[1] = f2bf(((xv[1] - mu) * rstd * gv.y + bv.y) * dv.y);
        pk[2] = f2bf(((xv[2] - mu) * rstd * gv.z + bv.z) * dv.z);
        pk[3] = f2bf(((xv[3] - mu) * rstd * gv.w + bv.w) * dv.w);
        reinterpret_cast<ushort4v*>(out + (size_t)row * TWOD)[tid] = pk;
    }
    {
        const float4 gv = reinterpret_cast<const float4*>(g)[256 + tid];
        const float4 bv = reinterpret_cast<const float4*>(bt)[256 + tid];
        const float4 dv = reinterpret_cast<const float4*>(dm)[256 + tid];
        ushort4v pk;
        pk[0] = f2bf(((hv[0] - mu) * rstd * gv.x + bv.x) * dv.x);
        pk[1] = f2bf(((hv[1] - mu) * rstd * gv.y + bv.y) * dv.y);
        pk[2] = f2bf(((hv[2] - mu) * rstd * gv.z + bv.z) * dv.z);
        pk[3] = f2bf(((hv[3] - mu) * rstd * gv.w + bv.w) * dv.w);
        reinterpret_cast<ushort4v*>(out + (size_t)row * TWOD + DDIM)[tid] = pk;
    }
}

// ---------------- 128x128 BK=64 m97-structure bf16 GEMM (R9) ---------------
// A : [16384][2048] bf16 row-major; BT: [N][2048] bf16 row-major.
// LDS: As[128][64] + Bs[128][64] bf16 (16KB each; 32KB -> 3 blocks/CU).
// Row = 128B = 8 granules. Swizzle: phys granule = logical ^ (row&7);
// stage SOURCE pre-XORed, dest linear, reads apply same XOR (0 conflicts).
// Grid: 1D XCD-chunk swizzled, y(N)-fastest decode (A-panel L2 locality).
template <int EPI>
__global__ __launch_bounds__(NTH, 3) void gemm97(const unsigned short* __restrict__ A,
                                                 const unsigned short* __restrict__ BT,
                                                 const float* __restrict__ bias,
                                                 const float* __restrict__ h,
                                                 const unsigned short* __restrict__ hb,
                                                 unsigned short* __restrict__ hr,
                                                 unsigned short* __restrict__ zb,
                                                 float* __restrict__ zf,
                                                 float* __restrict__ outp,
                                                 int NYB) {
    __shared__ unsigned short As[8192];   // [128][64] bf16, 16KB
    __shared__ unsigned short Bs[8192];
    const int tid  = threadIdx.x;
    const int lane = tid & 63;
    const int w    = tid >> 6;        // 0..3
    const int wm   = w >> 1;          // 0..1 (M-warp)
    const int wn   = w & 1;           // 0..1 (N-warp)
    const int q    = lane >> 4;       // 0..3 (K-chunk)
    const int r16  = lane & 15;

    // XCD-chunk swizzle (bijective: nwg % 8 == 0), y-fastest decode
    const int nwg = gridDim.x;
    const int cid = (blockIdx.x & 7) * (nwg >> 3) + (blockIdx.x >> 3);
    const size_t m0 = (size_t)(cid / NYB) * 128;
    const int    n0 = (cid % NYB) * 128;

    const unsigned short* Ag = A  + m0 * TWOD;
    const unsigned short* Bg = BT + (size_t)n0 * TWOD;

    // staging: tile = 128 rows x 8 granules = 1024 granules; thread t covers
    // granules t, t+256, t+512, t+768 (rows r0, r0+32, r0+64, r0+96).
    const int r0 = tid >> 3;                         // 0..31
    const int sg = (tid & 7) ^ (r0 & 7);
    const unsigned short* aS0 = Ag + (size_t)r0 * TWOD + sg * 8;
    const unsigned short* aS1 = Ag + (size_t)(r0 + 32) * TWOD + sg * 8;
    const unsigned short* aS2 = Ag + (size_t)(r0 + 64) * TWOD + sg * 8;
    const unsigned short* aS3 = Ag + (size_t)(r0 + 96) * TWOD + sg * 8;
    const unsigned short* bS0 = Bg + (size_t)r0 * TWOD + sg * 8;
    const unsigned short* bS1 = Bg + (size_t)(r0 + 32) * TWOD + sg * 8;
    const unsigned short* bS2 = Bg + (size_t)(r0 + 64) * TWOD + sg * 8;
    const unsigned short* bS3 = Bg + (size_t)(r0 + 96) * TWOD + sg * 8;
    const unsigned dst = (unsigned)w * 1024u;        // + lane*16 by HW

    // frag reads: row = (wm|wn)*64 + i*16 + r16; sub-k s, chunk q ->
    // phys granule = (s*4+q) ^ (r16&7); byte = row*128 + pg*16.
    const unsigned arow = (unsigned)((wm * 64 + r16) * 128);   // + i*2048
    const unsigned brow = (unsigned)((wn * 64 + r16) * 128);   // + n*2048
    const unsigned pg0  = (unsigned)(((0 * 4 + q) ^ (r16 & 7)) * 16);
    const unsigned pg1  = (unsigned)(((1 * 4 + q) ^ (r16 & 7)) * 16);

    f32x4 acc[4][4] = {};
    const int NT = TWOD / GBK;   // 32

    for (int T = 0; T < NT; ++T) {
        const int k_ = T * GBK;
        gload16(aS0 + k_, (char*)As + dst);
        gload16(aS1 + k_, (char*)As + dst + 4096u);
        gload16(aS2 + k_, (char*)As + dst + 8192u);
        gload16(aS3 + k_, (char*)As + dst + 12288u);
        gload16(bS0 + k_, (char*)Bs + dst);
        gload16(bS1 + k_, (char*)Bs + dst + 4096u);
        gload16(bS2 + k_, (char*)Bs + dst + 8192u);
        gload16(bS3 + k_, (char*)Bs + dst + 12288u);
        __syncthreads();                 // full drain (m97 semantics)
        {
            bf16x8 af[4], bfr[4];
#pragma unroll
            for (int n = 0; n < 4; ++n)
                bfr[n] = *(const bf16x8*)((const char*)Bs + brow + (unsigned)n * 2048u + pg0);
#pragma unroll
            for (int i = 0; i < 4; ++i)
                af[i] = *(const bf16x8*)((const char*)As + arow + (unsigned)i * 2048u + pg0);
#pragma unroll
            for (int i = 0; i < 4; ++i)
#pragma unroll
                for (int n = 0; n < 4; ++n)
                    acc[i][n] = __builtin_amdgcn_mfma_f32_16x16x32_bf16(af[i], bfr[n], acc[i][n], 0, 0, 0);
        }
        {
            bf16x8 af[4], bfr[4];
#pragma unroll
            for (int n = 0; n < 4; ++n)
                bfr[n] = *(const bf16x8*)((const char*)Bs + brow + (unsigned)n * 2048u + pg1);
#pragma unroll
            for (int i = 0; i < 4; ++i)
                af[i] = *(const bf16x8*)((const char*)As + arow + (unsigned)i * 2048u + pg1);
#pragma unroll
            for (int i = 0; i < 4; ++i)
#pragma unroll
                for (int n = 0; n < 4; ++n)
                    acc[i][n] = __builtin_amdgcn_mfma_f32_16x16x32_bf16(af[i], bfr[n], acc[i][n], 0, 0, 0);
        }
        __syncthreads();
    }

    // epilogue: D col = lane&15, row = (lane>>4)*4 + reg  [verified m89/m91]
#pragma unroll
    for (int n = 0; n < 4; ++n) {
        const int col = n0 + wn * 64 + n * 16 + r16;
        const float bc = bias[col];
#pragma unroll
        for (int m = 0; m < 4; ++m) {
#pragma unroll
            for (int rg = 0; rg < 4; ++rg) {
                const size_t row = m0 + wm * 64 + m * 16 + q * 4 + rg;
                const float v = acc[m][n][rg] + bc;
                if (EPI == 0) {
                    if (col < DDIM) {
                        const float rr = 1.0f / (1.0f + __expf(-v));
                        const size_t idx = row * DDIM + col;
                        const float hvv = hb ? bf2f(hb[idx]) : h[idx];
                        hr[idx] = f2bf(hvv * rr);
                    } else {
                        const float zz = 1.0f / (1.0f + __expf(-v));
                        const size_t zi = row * DDIM + (col - DDIM);
                        if (zb) zb[zi] = f2bf(zz); else zf[zi] = zz;
                    }
                } else {
                    const float u = tanhf(v);
                    const size_t idx = row * DDIM + col;
                    const float zz = zb ? bf2f(zb[idx]) : zf[idx];
                    const float hv = hb ? bf2f(hb[idx]) : h[idx];
                    outp[idx] = hv * zz + (1.0f - zz) * u;
                }
            }
        }
    }
}

// --------------------------------------------------------------------------
extern "C" void kernel_launch(void* const* d_in, const int* in_sizes, int n_in,
                              void* d_out, int out_size, void* d_ws, size_t ws_size,
                              hipStream_t stream) {
    const float* x  = (const float*)d_in[0];
    const float* h  = (const float*)d_in[1];
    const float* Wg = (const float*)d_in[2];
    const float* bg = (const float*)d_in[3];
    const float* Wu = (const float*)d_in[4];
    const float* bu = (const float*)d_in[5];
    const float* g1 = (const float*)d_in[6];
    const float* b1 = (const float*)d_in[7];
    const float* g2 = (const float*)d_in[8];
    const float* b2 = (const float*)d_in[9];
    const float* dm = (const float*)d_in[10];
    float* out = (float*)d_out;

    char* ws = (char*)d_ws;
    unsigned short* WgT = (unsigned short*)(ws);                    // 8 MB
    unsigned short* WuT = (unsigned short*)(ws + 8388608);          // 4 MB
    unsigned short* ln  = (unsigned short*)(ws + 12582912);         // 64 MB
    unsigned short* hr  = (unsigned short*)(ws + 79691776);         // 32 MB
    const bool big = (ws_size >= 180355072ull);
    unsigned short* zb = big ? (unsigned short*)(ws + 113246208) : nullptr;
    unsigned short* hb = big ? (unsigned short*)(ws + 146800640) : nullptr;

    wtrans<<<dim3(64, 64), 256, 0, stream>>>(Wg, WgT, TWOD, TWOD);
    wtrans<<<dim3(64, 32), 256, 0, stream>>>(Wu, WuT, TWOD, DDIM);
    ln_kernel<false><<<BATCH, 256, 0, stream>>>(x, (const void*)h, g1, b1, dm, ln, hb);
    // GEMM1: 128 M x 16 N = 2048 blocks (div 8 ok)
    gemm97<0><<<2048, NTH, 0, stream>>>(ln, WgT, bg, h, hb, hr, zb, out, nullptr, 16);
    ln_kernel<true><<<BATCH, 256, 0, stream>>>(x, (const void*)hr, g2, b2, dm, ln, nullptr);
    // GEMM2: 128 M x 8 N = 1024 blocks (div 8 ok)
    gemm97<1><<<1024, NTH, 0, stream>>>(ln, WuT, bu, h, hb, nullptr, zb, out, out, 8);
}

// Round 14
// 380.209 us; speedup vs baseline: 1.3252x; 1.0061x over previous
//
#include <hip/hip_runtime.h>
#include <hip/hip_bf16.h>

// GRUCell fused cell. B=16384, d=1024, 2d=2048.
//   inp  = LN(concat(x,h); g1,b1) * dm
//   gates= inp @ Wg + bg ; r=sig(gates[:, :d]); z=sig(gates[:, d:])
//   inp2 = LN(concat(x, h*r); g2,b2) * dm
//   u    = tanh(inp2 @ Wu + bu)
//   out  = h*z + (1-z)*u
//
// R14 = R13 with __launch_bounds__(256,4) on the GEMM: unified reg use is
// exactly 128/thread (64 VGPR + 64 AGPR) and LDS 32KB/block, so 4 blocks/CU
// (16 waves) fits (m69: waves halve at 128 regs -> 16/CU). Gains: (a) one
// more co-resident block hides the per-K-step staging drain (m114), (b)
// GEMM2's 1024 blocks become EXACTLY one co-resident round (vs 1.33), and
// GEMM1's 2048 exactly 2.0 rounds - no partial-tail idle.
//
// ws layout (bytes):
//   [0,            8388608)  WgT bf16 [2048][2048]
//   [8388608,     12582912)  WuT bf16 [1024][2048]
//   [12582912,    79691776)  ln  bf16 [16384][2048]
//   [79691776,   113246208)  hr  bf16 [16384][1024]
//   [113246208,  146800640)  zb  bf16 [16384][1024]   (big-ws only)
//   [146800640,  180355072)  hb  bf16 [16384][1024]   (big-ws only)

#define BATCH 16384
#define DDIM  1024
#define TWOD  2048
#define LNEPS 1e-5f

#define GBK 64
#define NTH 256

typedef __bf16 bf16x8 __attribute__((ext_vector_type(8)));
typedef float  f32x4  __attribute__((ext_vector_type(4)));
typedef unsigned short ushort4v __attribute__((ext_vector_type(4)));

__device__ __forceinline__ unsigned short f2bf(float f) {
    unsigned int u = __builtin_bit_cast(unsigned int, f);
    u = (u + 0x7FFFu + ((u >> 16) & 1u)) >> 16;   // round-to-nearest-even
    return (unsigned short)u;
}
__device__ __forceinline__ float bf2f(unsigned short s) {
    unsigned int u = ((unsigned int)s) << 16;
    return __builtin_bit_cast(float, u);
}
__device__ __forceinline__ void gload16(const void* g, void* l) {
    __builtin_amdgcn_global_load_lds((__attribute__((address_space(1))) void*)(g),
                                     (__attribute__((address_space(3))) void*)(l),
                                     16u, 0, 0);
}

// ---------------- weight transpose + f32->bf16 cast ------------------------
__global__ __launch_bounds__(256) void wtrans(const float* __restrict__ W,
                                              unsigned short* __restrict__ WT,
                                              int K, int N) {
    __shared__ float tile[32][33];
    const int k0 = blockIdx.x * 32;
    const int n0 = blockIdx.y * 32;
    const int tx = threadIdx.x & 31;
    const int ty = threadIdx.x >> 5;
#pragma unroll
    for (int p = 0; p < 32; p += 8)
        tile[p + ty][tx] = W[(size_t)(k0 + p + ty) * N + n0 + tx];
    __syncthreads();
#pragma unroll
    for (int p = 0; p < 32; p += 8)
        WT[(size_t)(n0 + p + ty) * K + k0 + tx] = f2bf(tile[tx][p + ty]);
}

// ---------------- fused LayerNorm over concat(x, second) -------------------
// hb_out != null (LN1 big-ws mode): also emit the h-half as bf16.
template <bool SECOND_BF16>
__global__ __launch_bounds__(256) void ln_kernel(const float* __restrict__ x,
                                                 const void* __restrict__ h2,
                                                 const float* __restrict__ g,
                                                 const float* __restrict__ bt,
                                                 const float* __restrict__ dm,
                                                 unsigned short* __restrict__ out,
                                                 unsigned short* __restrict__ hb_out) {
    const int row  = blockIdx.x;
    const int tid  = threadIdx.x;
    const int lane = tid & 63;
    const int w    = tid >> 6;

    const float4 xl = reinterpret_cast<const float4*>(x + (size_t)row * DDIM)[tid];
    float hv[4];
    if (SECOND_BF16) {
        const ushort4v hl = reinterpret_cast<const ushort4v*>(
            (const unsigned short*)h2 + (size_t)row * DDIM)[tid];
#pragma unroll
        for (int j = 0; j < 4; ++j) hv[j] = bf2f(hl[j]);
    } else {
        const float4 hl = reinterpret_cast<const float4*>(
            (const float*)h2 + (size_t)row * DDIM)[tid];
        hv[0] = hl.x; hv[1] = hl.y; hv[2] = hl.z; hv[3] = hl.w;
    }
    float xv[4] = {xl.x, xl.y, xl.z, xl.w};

    if (!SECOND_BF16 && hb_out) {
        ushort4v hp;
#pragma unroll
        for (int j = 0; j < 4; ++j) hp[j] = f2bf(hv[j]);
        reinterpret_cast<ushort4v*>(hb_out + (size_t)row * DDIM)[tid] = hp;
    }

    float s = 0.f, ss = 0.f;
#pragma unroll
    for (int j = 0; j < 4; ++j) { s += xv[j] + hv[j]; ss += xv[j]*xv[j] + hv[j]*hv[j]; }
#pragma unroll
    for (int o = 32; o; o >>= 1) { s += __shfl_xor(s, o); ss += __shfl_xor(ss, o); }
    __shared__ float red[8];
    if (lane == 0) { red[w] = s; red[4 + w] = ss; }
    __syncthreads();
    s  = red[0] + red[1] + red[2] + red[3];
    ss = red[4] + red[5] + red[6] + red[7];
    const float inv  = 1.0f / (float)TWOD;
    const float mu   = s * inv;
    const float var  = ss * inv - mu * mu;
    const float rstd = rsqrtf(var + LNEPS);

    {
        const float4 gv = reinterpret_cast<const float4*>(g)[tid];
        const float4 bv = reinterpret_cast<const float4*>(bt)[tid];
        const float4 dv = reinterpret_cast<const float4*>(dm)[tid];
        ushort4v pk;
        pk[0] = f2bf(((xv[0] - mu) * rstd * gv.x + bv.x) * dv.x);
        pk[1] = f2bf(((xv[1] - mu) * rstd * gv.y + bv.y) * dv.y);
        pk[2] = f2bf(((xv[2] - mu) * rstd * gv.z + bv.z) * dv.z);
        pk[3] = f2bf(((xv[3] - mu) * rstd * gv.w + bv.w) * dv.w);
        reinterpret_cast<ushort4v*>(out + (size_t)row * TWOD)[tid] = pk;
    }
    {
        const float4 gv = reinterpret_cast<const float4*>(g)[256 + tid];
        const float4 bv = reinterpret_cast<const float4*>(bt)[256 + tid];
        const float4 dv = reinterpret_cast<const float4*>(dm)[256 + tid];
        ushort4v pk;
        pk[0] = f2bf(((hv[0] - mu) * rstd * gv.x + bv.x) * dv.x);
        pk[1] = f2bf(((hv[1] - mu) * rstd * gv.y + bv.y) * dv.y);
        pk[2] = f2bf(((hv[2] - mu) * rstd * gv.z + bv.z) * dv.z);
        pk[3] = f2bf(((hv[3] - mu) * rstd * gv.w + bv.w) * dv.w);
        reinterpret_cast<ushort4v*>(out + (size_t)row * TWOD + DDIM)[tid] = pk;
    }
}

// ---------------- 128x128 BK=64 m97-structure bf16 GEMM --------------------
// A : [16384][2048] bf16 row-major; BT: [N][2048] bf16 row-major.
// LDS: As[128][64] + Bs[128][64] bf16 (16KB each; 32KB). 4 blocks/CU.
// Row = 128B = 8 granules. Swizzle: phys granule = logical ^ (row&7);
// stage SOURCE pre-XORed, dest linear, reads apply same XOR (0 conflicts).
// Grid: 1D XCD-chunk swizzled, y(N)-fastest decode (A-panel L2 locality).
template <int EPI>
__global__ __launch_bounds__(NTH, 4) void gemm97(const unsigned short* __restrict__ A,
                                                 const unsigned short* __restrict__ BT,
                                                 const float* __restrict__ bias,
                                                 const float* __restrict__ h,
                                                 const unsigned short* __restrict__ hb,
                                                 unsigned short* __restrict__ hr,
                                                 unsigned short* __restrict__ zb,
                                                 float* __restrict__ zf,
                                                 float* __restrict__ outp,
                                                 int NYB) {
    __shared__ unsigned short As[8192];   // [128][64] bf16, 16KB
    __shared__ unsigned short Bs[8192];
    const int tid  = threadIdx.x;
    const int lane = tid & 63;
    const int w    = tid >> 6;        // 0..3
    const int wm   = w >> 1;          // 0..1 (M-warp)
    const int wn   = w & 1;           // 0..1 (N-warp)
    const int q    = lane >> 4;       // 0..3 (K-chunk)
    const int r16  = lane & 15;

    // XCD-chunk swizzle (bijective: nwg % 8 == 0), y-fastest decode
    const int nwg = gridDim.x;
    const int cid = (blockIdx.x & 7) * (nwg >> 3) + (blockIdx.x >> 3);
    const size_t m0 = (size_t)(cid / NYB) * 128;
    const int    n0 = (cid % NYB) * 128;

    const unsigned short* Ag = A  + m0 * TWOD;
    const unsigned short* Bg = BT + (size_t)n0 * TWOD;

    // staging: tile = 128 rows x 8 granules = 1024 granules; thread t covers
    // granules t, t+256, t+512, t+768 (rows r0, r0+32, r0+64, r0+96).
    const int r0 = tid >> 3;                         // 0..31
    const int sg = (tid & 7) ^ (r0 & 7);
    const unsigned short* aS0 = Ag + (size_t)r0 * TWOD + sg * 8;
    const unsigned short* aS1 = Ag + (size_t)(r0 + 32) * TWOD + sg * 8;
    const unsigned short* aS2 = Ag + (size_t)(r0 + 64) * TWOD + sg * 8;
    const unsigned short* aS3 = Ag + (size_t)(r0 + 96) * TWOD + sg * 8;
    const unsigned short* bS0 = Bg + (size_t)r0 * TWOD + sg * 8;
    const unsigned short* bS1 = Bg + (size_t)(r0 + 32) * TWOD + sg * 8;
    const unsigned short* bS2 = Bg + (size_t)(r0 + 64) * TWOD + sg * 8;
    const unsigned short* bS3 = Bg + (size_t)(r0 + 96) * TWOD + sg * 8;
    const unsigned dst = (unsigned)w * 1024u;        // + lane*16 by HW

    // frag reads: row = (wm|wn)*64 + i*16 + r16; sub-k s, chunk q ->
    // phys granule = (s*4+q) ^ (r16&7); byte = row*128 + pg*16.
    const unsigned arow = (unsigned)((wm * 64 + r16) * 128);   // + i*2048
    const unsigned brow = (unsigned)((wn * 64 + r16) * 128);   // + n*2048
    const unsigned pg0  = (unsigned)(((0 * 4 + q) ^ (r16 & 7)) * 16);
    const unsigned pg1  = (unsigned)(((1 * 4 + q) ^ (r16 & 7)) * 16);

    f32x4 acc[4][4] = {};
    const int NT = TWOD / GBK;   // 32

    for (int T = 0; T < NT; ++T) {
        const int k_ = T * GBK;
        gload16(aS0 + k_, (char*)As + dst);
        gload16(aS1 + k_, (char*)As + dst + 4096u);
        gload16(aS2 + k_, (char*)As + dst + 8192u);
        gload16(aS3 + k_, (char*)As + dst + 12288u);
        gload16(bS0 + k_, (char*)Bs + dst);
        gload16(bS1 + k_, (char*)Bs + dst + 4096u);
        gload16(bS2 + k_, (char*)Bs + dst + 8192u);
        gload16(bS3 + k_, (char*)Bs + dst + 12288u);
        __syncthreads();                 // full drain (m97 semantics)
        {
            bf16x8 af[4], bfr[4];
#pragma unroll
            for (int n = 0; n < 4; ++n)
                bfr[n] = *(const bf16x8*)((const char*)Bs + brow + (unsigned)n * 2048u + pg0);
#pragma unroll
            for (int i = 0; i < 4; ++i)
                af[i] = *(const bf16x8*)((const char*)As + arow + (unsigned)i * 2048u + pg0);
#pragma unroll
            for (int i = 0; i < 4; ++i)
#pragma unroll
                for (int n = 0; n < 4; ++n)
                    acc[i][n] = __builtin_amdgcn_mfma_f32_16x16x32_bf16(af[i], bfr[n], acc[i][n], 0, 0, 0);
        }
        {
            bf16x8 af[4], bfr[4];
#pragma unroll
            for (int n = 0; n < 4; ++n)
                bfr[n] = *(const bf16x8*)((const char*)Bs + brow + (unsigned)n * 2048u + pg1);
#pragma unroll
            for (int i = 0; i < 4; ++i)
                af[i] = *(const bf16x8*)((const char*)As + arow + (unsigned)i * 2048u + pg1);
#pragma unroll
            for (int i = 0; i < 4; ++i)
#pragma unroll
                for (int n = 0; n < 4; ++n)
                    acc[i][n] = __builtin_amdgcn_mfma_f32_16x16x32_bf16(af[i], bfr[n], acc[i][n], 0, 0, 0);
        }
        __syncthreads();
    }

    // epilogue: D col = lane&15, row = (lane>>4)*4 + reg  [verified m89/m91]
#pragma unroll
    for (int n = 0; n < 4; ++n) {
        const int col = n0 + wn * 64 + n * 16 + r16;
        const float bc = bias[col];
#pragma unroll
        for (int m = 0; m < 4; ++m) {
#pragma unroll
            for (int rg = 0; rg < 4; ++rg) {
                const size_t row = m0 + wm * 64 + m * 16 + q * 4 + rg;
                const float v = acc[m][n][rg] + bc;
                if (EPI == 0) {
                    if (col < DDIM) {
                        const float rr = 1.0f / (1.0f + __expf(-v));
                        const size_t idx = row * DDIM + col;
                        const float hvv = hb ? bf2f(hb[idx]) : h[idx];
                        hr[idx] = f2bf(hvv * rr);
                    } else {
                        const float zz = 1.0f / (1.0f + __expf(-v));
                        const size_t zi = row * DDIM + (col - DDIM);
                        if (zb) zb[zi] = f2bf(zz); else zf[zi] = zz;
                    }
                } else {
                    const float u = tanhf(v);
                    const size_t idx = row * DDIM + col;
                    const float zz = zb ? bf2f(zb[idx]) : zf[idx];
                    const float hv = hb ? bf2f(hb[idx]) : h[idx];
                    outp[idx] = hv * zz + (1.0f - zz) * u;
                }
            }
        }
    }
}

// --------------------------------------------------------------------------
extern "C" void kernel_launch(void* const* d_in, const int* in_sizes, int n_in,
                              void* d_out, int out_size, void* d_ws, size_t ws_size,
                              hipStream_t stream) {
    const float* x  = (const float*)d_in[0];
    const float* h  = (const float*)d_in[1];
    const float* Wg = (const float*)d_in[2];
    const float* bg = (const float*)d_in[3];
    const float* Wu = (const float*)d_in[4];
    const float* bu = (const float*)d_in[5];
    const float* g1 = (const float*)d_in[6];
    const float* b1 = (const float*)d_in[7];
    const float* g2 = (const float*)d_in[8];
    const float* b2 = (const float*)d_in[9];
    const float* dm = (const float*)d_in[10];
    float* out = (float*)d_out;

    char* ws = (char*)d_ws;
    unsigned short* WgT = (unsigned short*)(ws);                    // 8 MB
    unsigned short* WuT = (unsigned short*)(ws + 8388608);          // 4 MB
    unsigned short* ln  = (unsigned short*)(ws + 12582912);         // 64 MB
    unsigned short* hr  = (unsigned short*)(ws + 79691776);         // 32 MB
    const bool big = (ws_size >= 180355072ull);
    unsigned short* zb = big ? (unsigned short*)(ws + 113246208) : nullptr;
    unsigned short* hb = big ? (unsigned short*)(ws + 146800640) : nullptr;

    wtrans<<<dim3(64, 64), 256, 0, stream>>>(Wg, WgT, TWOD, TWOD);
    wtrans<<<dim3(64, 32), 256, 0, stream>>>(Wu, WuT, TWOD, DDIM);
    ln_kernel<false><<<BATCH, 256, 0, stream>>>(x, (const void*)h, g1, b1, dm, ln, hb);
    // GEMM1: 128 M x 16 N = 2048 blocks (div 8 ok; = 2.0 rounds at 4 blk/CU)
    gemm97<0><<<2048, NTH, 0, stream>>>(ln, WgT, bg, h, hb, hr, zb, out, nullptr, 16);
    ln_kernel<true><<<BATCH, 256, 0, stream>>>(x, (const void*)hr, g2, b2, dm, ln, nullptr);
    // GEMM2: 128 M x 8 N = 1024 blocks (exactly 1 co-resident round)
    gemm97<1><<<1024, NTH, 0, stream>>>(ln, WuT, bu, h, hb, nullptr, zb, out, out, 8);
}